// Round 3
// baseline (269.517 us; speedup 1.0000x reference)
//
#include <hip/hip_runtime.h>
#include <hip/hip_bf16.h>
#include <cstdint>

typedef short short8 __attribute__((ext_vector_type(8)));
typedef float f32x4 __attribute__((ext_vector_type(4)));

#define MFMA16(a, b, c) __builtin_amdgcn_mfma_f32_16x16x32_bf16((a), (b), (c), 0, 0, 0)

__device__ __forceinline__ float b2f(unsigned short u) {
    unsigned x = ((unsigned)u) << 16;
    return __builtin_bit_cast(float, x);
}
__device__ __forceinline__ unsigned short f2b(float f) {
    __hip_bfloat16 h = __float2bfloat16(f);
    return __builtin_bit_cast(unsigned short, h);
}

__device__ __forceinline__ void gl_lds16(const void* g, void* l) {
    __builtin_amdgcn_global_load_lds((const __attribute__((address_space(1))) void*)g,
                                     (__attribute__((address_space(3))) void*)l, 16, 0, 0);
}

// (1/8) * log2(e): QK^T scores land in log2 domain -> bare v_exp_f32 softmax
#define QSC 0.18033688011112042f

// ---------------- RMSNorm: fp32 x -> bf16 xn ----------------
__global__ void rmsnorm_kernel(const float* __restrict__ x, const float* __restrict__ scale,
                               unsigned short* __restrict__ xn) {
    const int row = blockIdx.x;
    const int tid = threadIdx.x;
    const float4* xr = (const float4*)(x + (size_t)row * 1024);
    float4 vx = xr[tid];
    float ss = vx.x * vx.x + vx.y * vx.y + vx.z * vx.z + vx.w * vx.w;
#pragma unroll
    for (int m = 1; m < 64; m <<= 1) ss += __shfl_xor(ss, m);
    __shared__ float wsum[4];
    if ((tid & 63) == 0) wsum[tid >> 6] = ss;
    __syncthreads();
    float tot = wsum[0] + wsum[1] + wsum[2] + wsum[3];
    float rs = rsqrtf(tot * (1.0f / 1024.0f) + 1e-6f);
    const float4* sr = (const float4*)scale;
    float4 sv = sr[tid];
    ushort4 r;
    r.x = f2b(vx.x * sv.x * rs);
    r.y = f2b(vx.y * sv.y * rs);
    r.z = f2b(vx.z * sv.z * rs);
    r.w = f2b(vx.w * sv.w * rs);
    *(ushort4*)(xn + (size_t)row * 1024 + tid * 4) = r;
}

// ---------------- f32 -> bf16 convert ----------------
__global__ void f2b_kernel(const float* __restrict__ in, unsigned short* __restrict__ outp, int n4) {
    int i = blockIdx.x * 256 + threadIdx.x;
    if (i < n4) {
        float4 vv = ((const float4*)in)[i];
        ushort4 r;
        r.x = f2b(vv.x);
        r.y = f2b(vv.y);
        r.z = f2b(vv.z);
        r.w = f2b(vv.w);
        ((ushort4*)outp)[i] = r;
    }
}

// ---------------- GEMM C = A * B^T (A: MxK bf16 row-major, B: NxK bf16 row-major) ----
// EPI 0: scatter qkv -> q,k (B,H,S,D) bf16 (q scaled by QSC), v TRANSPOSED (B,H,D,S)
// EPI 1: out[m][n] = acc + skip[m][n]  (fp32)
constexpr int BM = 128, BN = 128, BK = 64, KDIM = 1024, NT = KDIM / BK;

template <int EPI>
__launch_bounds__(256, 2) __global__
    void gemm_bt(const unsigned short* __restrict__ A, const unsigned short* __restrict__ Bw,
                 unsigned short* __restrict__ qo, unsigned short* __restrict__ ko,
                 unsigned short* __restrict__ vo, const float* __restrict__ skip,
                 float* __restrict__ out) {
    __shared__ unsigned short As[2][BM * BK];
    __shared__ unsigned short Bs[2][BN * BK];
    const int tid = threadIdx.x;
    const int lane = tid & 63, w = tid >> 6;
    const int wr = w >> 1, wc = w & 1;
    const int lr = lane & 15, lg = lane >> 4;
    // XCD-aware bijective swizzle: each XCD gets 8 consecutive by-rows.
    constexpr int NBX = (EPI == 0) ? 24 : 8;
    const int f = blockIdx.x;
    const int xcd = f & 7, wloc = f >> 3;
    const int g = xcd * (NBX * 8) + wloc;
    const int bx = g % NBX, by = g / NBX;
    const int m0 = by * BM;
    const int n0 = bx * BN;
    const int NCOL = (EPI == 0) ? 3072 : 1024;

    f32x4 acc[4][4] = {};

    auto stage = [&](int buf, int kt) {
        const int k0 = kt * BK;
#pragma unroll
        for (int i = 0; i < 4; ++i) {
            int seg = i * 256 + tid;
            int row = seg >> 3, c8 = seg & 7;
            gl_lds16(A + (size_t)(m0 + row) * KDIM + k0 + c8 * 8,
                     &As[buf][(i * 256 + w * 64) * 8]);
            gl_lds16(Bw + (size_t)(n0 + row) * KDIM + k0 + c8 * 8,
                     &Bs[buf][(i * 256 + w * 64) * 8]);
        }
    };

    stage(0, 0);
    __syncthreads();
    int cur = 0;
    for (int kt = 0; kt < NT; ++kt) {
        if (kt + 1 < NT) stage(cur ^ 1, kt + 1);
#pragma unroll
        for (int kkc = 0; kkc < 2; ++kkc) {
            short8 a[4], b[4];
#pragma unroll
            for (int m = 0; m < 4; ++m)
                a[m] = *(const short8*)&As[cur][(wr * 64 + m * 16 + lr) * BK + kkc * 32 + lg * 8];
#pragma unroll
            for (int n = 0; n < 4; ++n)
                b[n] = *(const short8*)&Bs[cur][(wc * 64 + n * 16 + lr) * BK + kkc * 32 + lg * 8];
#pragma unroll
            for (int m = 0; m < 4; ++m)
#pragma unroll
                for (int n = 0; n < 4; ++n) acc[m][n] = MFMA16(a[m], b[n], acc[m][n]);
        }
        __syncthreads();
        cur ^= 1;
    }

    if (EPI == 0) {
#pragma unroll
        for (int m = 0; m < 4; ++m)
#pragma unroll
            for (int n = 0; n < 4; ++n) {
                int gcol = n0 + wc * 64 + n * 16 + lr;
                int c = gcol >> 10, h = (gcol >> 6) & 15, d = gcol & 63;
                int grow0 = m0 + wr * 64 + m * 16 + lg * 4;
                int b = grow0 >> 10, s0 = grow0 & 1023;
                if (c == 2) {
                    ushort4 r;
                    r.x = f2b(acc[m][n][0]);
                    r.y = f2b(acc[m][n][1]);
                    r.z = f2b(acc[m][n][2]);
                    r.w = f2b(acc[m][n][3]);
                    *(ushort4*)&vo[(((size_t)(b * 16 + h)) * 64 + d) * 1024 + s0] = r;
                } else {
                    unsigned short* dst = (c == 0) ? qo : ko;
                    float sc = (c == 0) ? QSC : 1.0f;
#pragma unroll
                    for (int j = 0; j < 4; ++j)
                        dst[(((size_t)(b * 16 + h)) * 1024 + s0 + j) * 64 + d] =
                            f2b(acc[m][n][j] * sc);
                }
            }
    } else {
#pragma unroll
        for (int m = 0; m < 4; ++m)
#pragma unroll
            for (int n = 0; n < 4; ++n) {
                int gcol = n0 + wc * 64 + n * 16 + lr;
#pragma unroll
                for (int j = 0; j < 4; ++j) {
                    int grow = m0 + wr * 64 + m * 16 + lg * 4 + j;
                    size_t idx = (size_t)grow * NCOL + gcol;
                    out[idx] = acc[m][n][j] + skip[idx];
                }
            }
    }
}

// ---------------- RoPE (in-place on q and k, bf16, layout (B,H,S,D)), vectorized ----
__global__ void rope_kernel(unsigned short* __restrict__ q, unsigned short* __restrict__ k,
                            const float* __restrict__ theta) {
    int gid = blockIdx.x * 256 + threadIdx.x;  // 128 * 1024 * 2
    int bh = gid >> 11;
    int r = gid & 2047;
    int s = r >> 1, half = r & 1;
    int h = bh & 15;
    int d0 = half * 8;
    size_t base = (size_t)bh * 65536 + (size_t)s * 64 + d0;
    const float* thp = theta + ((size_t)s * 16 + h) * 16 + d0;
    float4 t0 = *(const float4*)thp;
    float4 t1 = *(const float4*)(thp + 4);
    float th[8] = {t0.x, t0.y, t0.z, t0.w, t1.x, t1.y, t1.z, t1.w};
    float sn[8], cs[8];
#pragma unroll
    for (int j = 0; j < 8; ++j) __sincosf(th[j], &sn[j], &cs[j]);
#pragma unroll
    for (int t = 0; t < 2; ++t) {
        unsigned short* p = (t == 0) ? q : k;
        short8 x1 = *(short8*)(p + base);
        short8 x2 = *(short8*)(p + base + 16);
        short8 y1, y2;
#pragma unroll
        for (int j = 0; j < 8; ++j) {
            float a = b2f((unsigned short)x1[j]), b = b2f((unsigned short)x2[j]);
            y1[j] = (short)f2b(a * cs[j] - b * sn[j]);
            y2[j] = (short)f2b(b * cs[j] + a * sn[j]);
        }
        *(short8*)(p + base) = y1;
        *(short8*)(p + base + 16) = y2;
    }
}

// ---------------- Flash attention (causal) ----------------
// q,k: (B,H,S,D) bf16 (q pre-scaled by QSC).  vT: (B,H,D,S) bf16.  o: (B,S,H*D) bf16.
// K and V^T both staged via global_load_lds with source-XOR swizzle; double-buffered;
// exp2-domain online softmax with defer-max; XCD-locality block swizzle.
__launch_bounds__(256, 3) __global__
    void attn_kernel(const unsigned short* __restrict__ q, const unsigned short* __restrict__ k,
                     const unsigned short* __restrict__ vt, unsigned short* __restrict__ o) {
    constexpr int S = 1024, D = 64;
    __shared__ unsigned short Ks[2][64 * 64];  // [t][d], chunk-swizzled
    __shared__ unsigned short Vs[2][64 * 64];  // [d][t], chunk-swizzled
    __shared__ unsigned short Ps[4][16][72];   // per-wave P[q][t]
    const int tid = threadIdx.x, lane = tid & 63, w = tid >> 6;
    const int lr = lane & 15, lg = lane >> 4;
    // bijective: all 16 qb-tiles of a bh on one XCD, qb descending (heavy first)
    const int f = blockIdx.x;
    const int xcd = f & 7, slot = f >> 3;
    const int bh = xcd * 16 + (slot >> 4);
    const int qb = 15 - (slot & 15);
    const int qs = qb * 64;
    const size_t base = (size_t)bh * (S * D);

    short8 qf[2];
    {
        const unsigned short* qp = q + base + (size_t)(qs + w * 16 + lr) * D;
        qf[0] = *(const short8*)(qp + lg * 8);
        qf[1] = *(const short8*)(qp + 32 + lg * 8);
    }

    f32x4 of[4] = {};
    float mrun[4], lrun[4];
#pragma unroll
    for (int j = 0; j < 4; ++j) {
        mrun[j] = -1e30f;
        lrun[j] = 0.f;
    }

    const int nkt = qb + 1;

    auto stageK = [&](int buf, int kt) {
#pragma unroll
        for (int i = 0; i < 2; ++i) {
            int seg = i * 256 + tid;
            int row = seg >> 3, c8 = (seg & 7) ^ (row & 7);
            gl_lds16(k + base + (size_t)(kt * 64 + row) * D + c8 * 8,
                     &Ks[buf][(i * 256 + w * 64) * 8]);
        }
    };
    auto stageV = [&](int buf, int kt) {
#pragma unroll
        for (int i = 0; i < 2; ++i) {
            int seg = i * 256 + tid;
            int row = seg >> 3, c8 = (seg & 7) ^ (row & 7);
            gl_lds16(vt + base + (size_t)row * S + kt * 64 + c8 * 8,
                     &Vs[buf][(i * 256 + w * 64) * 8]);
        }
    };

    stageK(0, 0);
    stageV(0, 0);
    __syncthreads();

    for (int kt = 0; kt < nkt; ++kt) {
        const int b = kt & 1;
        if (kt + 1 < nkt) {
            stageK(b ^ 1, kt + 1);
            stageV(b ^ 1, kt + 1);
        }

        // QK^T (log2-domain scores); swizzled Ks reads
        f32x4 sf[4] = {};
#pragma unroll
        for (int n = 0; n < 4; ++n) {
            const int r = n * 16 + lr;
#pragma unroll
            for (int kkc = 0; kkc < 2; ++kkc) {
                short8 bf = *(const short8*)&Ks[b][r * 64 + (((kkc * 4 + lg) ^ (lr & 7)) * 8)];
                sf[n] = MFMA16(qf[kkc], bf, sf[n]);
            }
        }

        if (kt == qb) {
#pragma unroll
            for (int n = 0; n < 4; ++n)
#pragma unroll
                for (int j = 0; j < 4; ++j) {
                    int qr = w * 16 + lg * 4 + j;
                    int t = n * 16 + lr;
                    if (t > qr) sf[n][j] = -1e30f;
                }
        }

        // online softmax (exp2 domain, defer-max THR=8)
#pragma unroll
        for (int j = 0; j < 4; ++j) {
            float mx = fmaxf(fmaxf(sf[0][j], sf[1][j]), fmaxf(sf[2][j], sf[3][j]));
            mx = fmaxf(mx, __shfl_xor(mx, 1));
            mx = fmaxf(mx, __shfl_xor(mx, 2));
            mx = fmaxf(mx, __shfl_xor(mx, 4));
            mx = fmaxf(mx, __shfl_xor(mx, 8));
            if (__any(mx > mrun[j] + 8.0f)) {
                float newm = fmaxf(mrun[j], mx);
                float sc = __builtin_amdgcn_exp2f(mrun[j] - newm);
                mrun[j] = newm;
                float psum = 0.f;
#pragma unroll
                for (int n = 0; n < 4; ++n) {
                    float p = __builtin_amdgcn_exp2f(sf[n][j] - newm);
                    sf[n][j] = p;
                    psum += p;
                }
                lrun[j] = lrun[j] * sc + psum;
#pragma unroll
                for (int n2 = 0; n2 < 4; ++n2) of[n2][j] *= sc;
            } else {
                float mo = mrun[j];
                float psum = 0.f;
#pragma unroll
                for (int n = 0; n < 4; ++n) {
                    float p = __builtin_amdgcn_exp2f(sf[n][j] - mo);
                    sf[n][j] = p;
                    psum += p;
                }
                lrun[j] += psum;
            }
        }

        // P -> LDS (per-wave, bf16, hw convert)
#pragma unroll
        for (int n = 0; n < 4; ++n)
#pragma unroll
            for (int j = 0; j < 4; ++j) Ps[w][lg * 4 + j][n * 16 + lr] = f2b(sf[n][j]);

        // PV: O[q][d] += P[q][t] * V[t][d], B-fragment from V^T (swizzled like K)
#pragma unroll
        for (int kkc = 0; kkc < 2; ++kkc) {
            short8 pa = *(const short8*)&Ps[w][lr][kkc * 32 + lg * 8];
#pragma unroll
            for (int n2 = 0; n2 < 4; ++n2) {
                const int r = n2 * 16 + lr;
                short8 bv = *(const short8*)&Vs[b][r * 64 + (((kkc * 4 + lg) ^ (lr & 7)) * 8)];
                of[n2] = MFMA16(pa, bv, of[n2]);
            }
        }

        __syncthreads();
    }

#pragma unroll
    for (int j = 0; j < 4; ++j) {
        float l = lrun[j];
        l += __shfl_xor(l, 1);
        l += __shfl_xor(l, 2);
        l += __shfl_xor(l, 4);
        l += __shfl_xor(l, 8);
        float inv = 1.f / l;
        int srow = qs + w * 16 + lg * 4 + j;
        int b = bh >> 4, h = bh & 15;
        size_t ob = ((size_t)(b * 1024 + srow)) * 1024 + h * 64;
#pragma unroll
        for (int n2 = 0; n2 < 4; ++n2) o[ob + n2 * 16 + lr] = f2b(of[n2][j] * inv);
    }
}

extern "C" void kernel_launch(void* const* d_in, const int* in_sizes, int n_in, void* d_out,
                              int out_size, void* d_ws, size_t ws_size, hipStream_t stream) {
    const float* x = (const float*)d_in[0];
    const float* scale = (const float*)d_in[1];
    const float* w_qkv = (const float*)d_in[2];
    const float* w_out = (const float*)d_in[3];
    const float* theta = (const float*)d_in[4];
    float* out = (float*)d_out;

    char* p = (char*)d_ws;
    unsigned short* xn = (unsigned short*)p;      p += (size_t)8192 * 1024 * 2;
    unsigned short* wqb = (unsigned short*)p;     p += (size_t)3072 * 1024 * 2;
    unsigned short* wob = (unsigned short*)p;     p += (size_t)1024 * 1024 * 2;
    unsigned short* qb_ = (unsigned short*)p;     p += (size_t)128 * 1024 * 64 * 2;
    unsigned short* kb_ = (unsigned short*)p;     p += (size_t)128 * 1024 * 64 * 2;
    unsigned short* vb_ = (unsigned short*)p;     p += (size_t)128 * 1024 * 64 * 2;  // V^T (B,H,D,S)
    unsigned short* ob_ = (unsigned short*)p;     p += (size_t)8192 * 1024 * 2;

    rmsnorm_kernel<<<8192, 256, 0, stream>>>(x, scale, xn);
    f2b_kernel<<<3072, 256, 0, stream>>>(w_qkv, wqb, 786432);
    f2b_kernel<<<1024, 256, 0, stream>>>(w_out, wob, 262144);
    gemm_bt<0><<<1536, 256, 0, stream>>>(xn, wqb, qb_, kb_, vb_, nullptr, nullptr);
    rope_kernel<<<1024, 256, 0, stream>>>(qb_, kb_, theta);
    attn_kernel<<<2048, 256, 0, stream>>>(qb_, kb_, vb_, ob_);
    gemm_bt<1><<<512, 256, 0, stream>>>(ob_, wob, nullptr, nullptr, nullptr, x, out);
}

// Round 4
// 250.522 us; speedup vs baseline: 1.0758x; 1.0758x over previous
//
#include <hip/hip_runtime.h>
#include <hip/hip_bf16.h>
#include <cstdint>

typedef short short8 __attribute__((ext_vector_type(8)));
typedef float f32x4 __attribute__((ext_vector_type(4)));

#define MFMA16(a, b, c) __builtin_amdgcn_mfma_f32_16x16x32_bf16((a), (b), (c), 0, 0, 0)

__device__ __forceinline__ float b2f(unsigned short u) {
    unsigned x = ((unsigned)u) << 16;
    return __builtin_bit_cast(float, x);
}
__device__ __forceinline__ unsigned short f2b(float f) {
    __hip_bfloat16 h = __float2bfloat16(f);
    return __builtin_bit_cast(unsigned short, h);
}

__device__ __forceinline__ void gl_lds16(const void* g, void* l) {
    __builtin_amdgcn_global_load_lds((const __attribute__((address_space(1))) void*)g,
                                     (__attribute__((address_space(3))) void*)l, 16, 0, 0);
}

// (1/8) * log2(e): QK^T scores land in log2 domain -> bare v_exp_f32 softmax
#define QSC 0.18033688011112042f

// ---------------- RMSNorm: fp32 x -> bf16 xn ----------------
__global__ void rmsnorm_kernel(const float* __restrict__ x, const float* __restrict__ scale,
                               unsigned short* __restrict__ xn) {
    const int row = blockIdx.x;
    const int tid = threadIdx.x;
    const float4* xr = (const float4*)(x + (size_t)row * 1024);
    float4 vx = xr[tid];
    float ss = vx.x * vx.x + vx.y * vx.y + vx.z * vx.z + vx.w * vx.w;
#pragma unroll
    for (int m = 1; m < 64; m <<= 1) ss += __shfl_xor(ss, m);
    __shared__ float wsum[4];
    if ((tid & 63) == 0) wsum[tid >> 6] = ss;
    __syncthreads();
    float tot = wsum[0] + wsum[1] + wsum[2] + wsum[3];
    float rs = rsqrtf(tot * (1.0f / 1024.0f) + 1e-6f);
    const float4* sr = (const float4*)scale;
    float4 sv = sr[tid];
    ushort4 r;
    r.x = f2b(vx.x * sv.x * rs);
    r.y = f2b(vx.y * sv.y * rs);
    r.z = f2b(vx.z * sv.z * rs);
    r.w = f2b(vx.w * sv.w * rs);
    *(ushort4*)(xn + (size_t)row * 1024 + tid * 4) = r;
}

// ---------------- f32 -> bf16 convert ----------------
__global__ void f2b_kernel(const float* __restrict__ in, unsigned short* __restrict__ outp, int n4) {
    int i = blockIdx.x * 256 + threadIdx.x;
    if (i < n4) {
        float4 vv = ((const float4*)in)[i];
        ushort4 r;
        r.x = f2b(vv.x);
        r.y = f2b(vv.y);
        r.z = f2b(vv.z);
        r.w = f2b(vv.w);
        ((ushort4*)outp)[i] = r;
    }
}

// ---------------- GEMM C = A * B^T (A: MxK bf16 row-major, B: NxK bf16 row-major) ----
// EPI 0: scatter qkv; RoPE fused for q,k (q scaled by QSC); v TRANSPOSED (B,H,D,S)
// EPI 1: out[m][n] = acc + skip[m][n]  (fp32)
constexpr int BM = 128, BN = 128, BK = 64, KDIM = 1024, NT = KDIM / BK;

template <int EPI>
__launch_bounds__(256, 2) __global__
    void gemm_bt(const unsigned short* __restrict__ A, const unsigned short* __restrict__ Bw,
                 unsigned short* __restrict__ qo, unsigned short* __restrict__ ko,
                 unsigned short* __restrict__ vo, const float* __restrict__ skip,
                 float* __restrict__ out, const float* __restrict__ theta) {
    __shared__ unsigned short As[2][BM * BK];
    __shared__ unsigned short Bs[2][BN * BK];
    const int tid = threadIdx.x;
    const int lane = tid & 63, w = tid >> 6;
    const int wr = w >> 1, wc = w & 1;
    const int lr = lane & 15, lg = lane >> 4;
    // XCD-aware bijective swizzle: each XCD gets 8 consecutive by-rows.
    constexpr int NBX = (EPI == 0) ? 24 : 8;
    const int f = blockIdx.x;
    const int xcd = f & 7, wloc = f >> 3;
    const int g = xcd * (NBX * 8) + wloc;
    const int bx = g % NBX, by = g / NBX;
    const int m0 = by * BM;
    const int n0 = bx * BN;
    const int NCOL = (EPI == 0) ? 3072 : 1024;

    f32x4 acc[4][4] = {};

    auto stage = [&](int buf, int kt) {
        const int k0 = kt * BK;
#pragma unroll
        for (int i = 0; i < 4; ++i) {
            int seg = i * 256 + tid;
            int row = seg >> 3, c8 = seg & 7;
            gl_lds16(A + (size_t)(m0 + row) * KDIM + k0 + c8 * 8,
                     &As[buf][(i * 256 + w * 64) * 8]);
            gl_lds16(Bw + (size_t)(n0 + row) * KDIM + k0 + c8 * 8,
                     &Bs[buf][(i * 256 + w * 64) * 8]);
        }
    };

    stage(0, 0);
    __syncthreads();
    int cur = 0;
    for (int kt = 0; kt < NT; ++kt) {
        if (kt + 1 < NT) stage(cur ^ 1, kt + 1);
#pragma unroll
        for (int kkc = 0; kkc < 2; ++kkc) {
            short8 a[4], b[4];
#pragma unroll
            for (int m = 0; m < 4; ++m)
                a[m] = *(const short8*)&As[cur][(wr * 64 + m * 16 + lr) * BK + kkc * 32 + lg * 8];
#pragma unroll
            for (int n = 0; n < 4; ++n)
                b[n] = *(const short8*)&Bs[cur][(wc * 64 + n * 16 + lr) * BK + kkc * 32 + lg * 8];
#pragma unroll
            for (int m = 0; m < 4; ++m)
#pragma unroll
                for (int n = 0; n < 4; ++n) acc[m][n] = MFMA16(a[m], b[n], acc[m][n]);
        }
        __syncthreads();
        cur ^= 1;
    }

    if (EPI == 0) {
        // whole (block, wc) group is one output tensor c and one head h
        const int colb = n0 + wc * 64;
        const int c = colb >> 10, h = (colb >> 6) & 15;
#pragma unroll
        for (int m = 0; m < 4; ++m) {
            int grow0 = m0 + wr * 64 + m * 16 + lg * 4;
            int b = grow0 >> 10, s0 = grow0 & 1023;
            if (c == 2) {
#pragma unroll
                for (int n = 0; n < 4; ++n) {
                    int d = n * 16 + lr;
                    ushort4 r;
                    r.x = f2b(acc[m][n][0]);
                    r.y = f2b(acc[m][n][1]);
                    r.z = f2b(acc[m][n][2]);
                    r.w = f2b(acc[m][n][3]);
                    *(ushort4*)&vo[(((size_t)(b * 16 + h)) * 64 + d) * 1024 + s0] = r;
                }
            } else {
                unsigned short* dst = (c == 0) ? qo : ko;
                float sc = (c == 0) ? QSC : 1.0f;
#pragma unroll
                for (int j = 0; j < 4; ++j) {
                    int s = s0 + j;
                    float th = theta[((s * 16 + h) << 4) + lr];
                    float sn, cs;
                    __sincosf(th, &sn, &cs);
                    float x1 = acc[m][0][j], x2 = acc[m][1][j];
                    size_t rowb = (((size_t)(b * 16 + h)) * 1024 + s) * 64;
                    dst[rowb + lr]      = f2b((x1 * cs - x2 * sn) * sc);
                    dst[rowb + 16 + lr] = f2b((x2 * cs + x1 * sn) * sc);
                    dst[rowb + 32 + lr] = f2b(acc[m][2][j] * sc);
                    dst[rowb + 48 + lr] = f2b(acc[m][3][j] * sc);
                }
            }
        }
    } else {
#pragma unroll
        for (int m = 0; m < 4; ++m)
#pragma unroll
            for (int n = 0; n < 4; ++n) {
                int gcol = n0 + wc * 64 + n * 16 + lr;
#pragma unroll
                for (int j = 0; j < 4; ++j) {
                    int grow = m0 + wr * 64 + m * 16 + lg * 4 + j;
                    size_t idx = (size_t)grow * NCOL + gcol;
                    out[idx] = acc[m][n][j] + skip[idx];
                }
            }
    }
}

// ---------------- Flash attention (causal), QBLK=128 ----------------
// q,k: (B,H,S,D) bf16 (q pre-scaled by QSC, rope applied).  vT: (B,H,D,S) bf16.
// o: (B,S,H*D) bf16. 4 waves x 32 q-rows; K/V^T staged via global_load_lds
// (source-XOR swizzle), double-buffered; exp2-domain online softmax with
// defer-max; per-wave causal tail skip; XCD-locality block swizzle.
__launch_bounds__(256, 3) __global__
    void attn_kernel(const unsigned short* __restrict__ q, const unsigned short* __restrict__ k,
                     const unsigned short* __restrict__ vt, unsigned short* __restrict__ o) {
    constexpr int S = 1024, D = 64;
    __shared__ unsigned short Ks[2][64 * 64];  // [t][d], chunk-swizzled
    __shared__ unsigned short Vs[2][64 * 64];  // [d][t], chunk-swizzled
    __shared__ unsigned short Ps[4][32][76];   // per-wave P[q][t]
    const int tid = threadIdx.x, lane = tid & 63, w = tid >> 6;
    const int lr = lane & 15, lg = lane >> 4;
    // bijective: all 8 qb-tiles of a bh on one XCD, qb descending (heavy first)
    const int f = blockIdx.x;  // 0..1023
    const int xcd = f & 7, slot = f >> 3;
    const int bh = xcd * 16 + (slot >> 3);
    const int qb = 7 - (slot & 7);
    const int qs = qb * 128;
    const size_t base = (size_t)bh * (S * D);
    const int wrow0 = qs + w * 32;

    short8 qf[2][2];
#pragma unroll
    for (int m = 0; m < 2; ++m) {
        const unsigned short* qp = q + base + (size_t)(wrow0 + m * 16 + lr) * D;
        qf[m][0] = *(const short8*)(qp + lg * 8);
        qf[m][1] = *(const short8*)(qp + 32 + lg * 8);
    }

    f32x4 of[2][4] = {};
    float mrun[2][4], lrun[2][4];
#pragma unroll
    for (int m = 0; m < 2; ++m)
#pragma unroll
        for (int j = 0; j < 4; ++j) {
            mrun[m][j] = -1e30f;
            lrun[m][j] = 0.f;
        }

    const int nkt = 2 * qb + 2;

    auto stageK = [&](int buf, int kt) {
#pragma unroll
        for (int i = 0; i < 2; ++i) {
            int seg = i * 256 + tid;
            int row = seg >> 3, c8 = (seg & 7) ^ (row & 7);
            gl_lds16(k + base + (size_t)(kt * 64 + row) * D + c8 * 8,
                     &Ks[buf][(i * 256 + w * 64) * 8]);
        }
    };
    auto stageV = [&](int buf, int kt) {
#pragma unroll
        for (int i = 0; i < 2; ++i) {
            int seg = i * 256 + tid;
            int row = seg >> 3, c8 = (seg & 7) ^ (row & 7);
            gl_lds16(vt + base + (size_t)row * S + kt * 64 + c8 * 8,
                     &Vs[buf][(i * 256 + w * 64) * 8]);
        }
    };

    stageK(0, 0);
    stageV(0, 0);
    __syncthreads();

    for (int kt = 0; kt < nkt; ++kt) {
        const int b = kt & 1;
        if (kt + 1 < nkt) {
            stageK(b ^ 1, kt + 1);
            stageV(b ^ 1, kt + 1);
        }

        if (kt * 64 <= wrow0 + 31) {  // wave-uniform: this wave has unmasked rows
            // QK^T (log2-domain scores); swizzled Ks reads, B-frag shared across m
            f32x4 sf[2][4] = {};
#pragma unroll
            for (int n = 0; n < 4; ++n) {
                const int r = n * 16 + lr;
#pragma unroll
                for (int kkc = 0; kkc < 2; ++kkc) {
                    short8 bf = *(const short8*)&Ks[b][r * 64 + (((kkc * 4 + lg) ^ (lr & 7)) * 8)];
#pragma unroll
                    for (int m = 0; m < 2; ++m) sf[m][n] = MFMA16(qf[m][kkc], bf, sf[m][n]);
                }
            }

            if (kt * 64 + 63 > wrow0) {  // tile overlaps diagonal for this wave
#pragma unroll
                for (int m = 0; m < 2; ++m)
#pragma unroll
                    for (int n = 0; n < 4; ++n)
#pragma unroll
                        for (int j = 0; j < 4; ++j) {
                            int qr = wrow0 + m * 16 + lg * 4 + j;
                            int t = kt * 64 + n * 16 + lr;
                            if (t > qr) sf[m][n][j] = -1e30f;
                        }
            }

            // online softmax (exp2 domain, defer-max THR=8)
#pragma unroll
            for (int m = 0; m < 2; ++m)
#pragma unroll
                for (int j = 0; j < 4; ++j) {
                    float mx = fmaxf(fmaxf(sf[m][0][j], sf[m][1][j]),
                                     fmaxf(sf[m][2][j], sf[m][3][j]));
                    mx = fmaxf(mx, __shfl_xor(mx, 1));
                    mx = fmaxf(mx, __shfl_xor(mx, 2));
                    mx = fmaxf(mx, __shfl_xor(mx, 4));
                    mx = fmaxf(mx, __shfl_xor(mx, 8));
                    if (__any(mx > mrun[m][j] + 8.0f)) {
                        float newm = fmaxf(mrun[m][j], mx);
                        float sc = __builtin_amdgcn_exp2f(mrun[m][j] - newm);
                        mrun[m][j] = newm;
                        float psum = 0.f;
#pragma unroll
                        for (int n = 0; n < 4; ++n) {
                            float p = __builtin_amdgcn_exp2f(sf[m][n][j] - newm);
                            sf[m][n][j] = p;
                            psum += p;
                        }
                        lrun[m][j] = lrun[m][j] * sc + psum;
#pragma unroll
                        for (int n2 = 0; n2 < 4; ++n2) of[m][n2][j] *= sc;
                    } else {
                        float mo = mrun[m][j];
                        float psum = 0.f;
#pragma unroll
                        for (int n = 0; n < 4; ++n) {
                            float p = __builtin_amdgcn_exp2f(sf[m][n][j] - mo);
                            sf[m][n][j] = p;
                            psum += p;
                        }
                        lrun[m][j] += psum;
                    }
                }

            // P -> LDS (per-wave, bf16)
#pragma unroll
            for (int m = 0; m < 2; ++m)
#pragma unroll
                for (int n = 0; n < 4; ++n)
#pragma unroll
                    for (int j = 0; j < 4; ++j)
                        Ps[w][m * 16 + lg * 4 + j][n * 16 + lr] = f2b(sf[m][n][j]);

            // PV: O[q][d] += P[q][t] * V[t][d]; bv shared across m
#pragma unroll
            for (int kkc = 0; kkc < 2; ++kkc) {
                short8 pa[2];
#pragma unroll
                for (int m = 0; m < 2; ++m)
                    pa[m] = *(const short8*)&Ps[w][m * 16 + lr][kkc * 32 + lg * 8];
#pragma unroll
                for (int n2 = 0; n2 < 4; ++n2) {
                    const int r = n2 * 16 + lr;
                    short8 bv = *(const short8*)&Vs[b][r * 64 + (((kkc * 4 + lg) ^ (lr & 7)) * 8)];
#pragma unroll
                    for (int m = 0; m < 2; ++m) of[m][n2] = MFMA16(pa[m], bv, of[m][n2]);
                }
            }
        }

        __syncthreads();
    }

    const int bb = bh >> 4, h = bh & 15;
#pragma unroll
    for (int m = 0; m < 2; ++m)
#pragma unroll
        for (int j = 0; j < 4; ++j) {
            float l = lrun[m][j];
            l += __shfl_xor(l, 1);
            l += __shfl_xor(l, 2);
            l += __shfl_xor(l, 4);
            l += __shfl_xor(l, 8);
            float inv = 1.f / l;
            int srow = wrow0 + m * 16 + lg * 4 + j;
            size_t ob = ((size_t)(bb * 1024 + srow)) * 1024 + h * 64;
#pragma unroll
            for (int n2 = 0; n2 < 4; ++n2) o[ob + n2 * 16 + lr] = f2b(of[m][n2][j] * inv);
        }
}

extern "C" void kernel_launch(void* const* d_in, const int* in_sizes, int n_in, void* d_out,
                              int out_size, void* d_ws, size_t ws_size, hipStream_t stream) {
    const float* x = (const float*)d_in[0];
    const float* scale = (const float*)d_in[1];
    const float* w_qkv = (const float*)d_in[2];
    const float* w_out = (const float*)d_in[3];
    const float* theta = (const float*)d_in[4];
    float* out = (float*)d_out;

    char* p = (char*)d_ws;
    unsigned short* xn = (unsigned short*)p;      p += (size_t)8192 * 1024 * 2;
    unsigned short* wqb = (unsigned short*)p;     p += (size_t)3072 * 1024 * 2;
    unsigned short* wob = (unsigned short*)p;     p += (size_t)1024 * 1024 * 2;
    unsigned short* qb_ = (unsigned short*)p;     p += (size_t)128 * 1024 * 64 * 2;
    unsigned short* kb_ = (unsigned short*)p;     p += (size_t)128 * 1024 * 64 * 2;
    unsigned short* vb_ = (unsigned short*)p;     p += (size_t)128 * 1024 * 64 * 2;  // V^T (B,H,D,S)
    unsigned short* ob_ = (unsigned short*)p;     p += (size_t)8192 * 1024 * 2;

    rmsnorm_kernel<<<8192, 256, 0, stream>>>(x, scale, xn);
    f2b_kernel<<<3072, 256, 0, stream>>>(w_qkv, wqb, 786432);
    f2b_kernel<<<1024, 256, 0, stream>>>(w_out, wob, 262144);
    gemm_bt<0><<<1536, 256, 0, stream>>>(xn, wqb, qb_, kb_, vb_, nullptr, nullptr, theta);
    attn_kernel<<<1024, 256, 0, stream>>>(qb_, kb_, vb_, ob_);
    gemm_bt<1><<<512, 256, 0, stream>>>(ob_, wob, nullptr, nullptr, nullptr, x, out, nullptr);
}

// Round 6
// 226.651 us; speedup vs baseline: 1.1891x; 1.1053x over previous
//
#include <hip/hip_runtime.h>
#include <hip/hip_bf16.h>
#include <cstdint>

typedef short short8 __attribute__((ext_vector_type(8)));
typedef float f32x4 __attribute__((ext_vector_type(4)));
typedef unsigned uint4v __attribute__((ext_vector_type(4)));

#define MFMA16(a, b, c) __builtin_amdgcn_mfma_f32_16x16x32_bf16((a), (b), (c), 0, 0, 0)

__device__ __forceinline__ unsigned short f2b(float f) {
    __hip_bfloat16 h = __float2bfloat16(f);
    return __builtin_bit_cast(unsigned short, h);
}

__device__ __forceinline__ void gl_lds16(const void* g, void* l) {
    __builtin_amdgcn_global_load_lds((const __attribute__((address_space(1))) void*)g,
                                     (__attribute__((address_space(3))) void*)l, 16, 0, 0);
}

// (1/8) * log2(e): QK^T scores land in log2 domain -> bare v_exp_f32 softmax
#define QSC 0.18033688011112042f

// ---------------- RMSNorm: fp32 x -> bf16 xn ----------------
__global__ void rmsnorm_kernel(const float* __restrict__ x, const float* __restrict__ scale,
                               unsigned short* __restrict__ xn) {
    const int row = blockIdx.x;
    const int tid = threadIdx.x;
    const float4* xr = (const float4*)(x + (size_t)row * 1024);
    float4 vx = xr[tid];
    float ss = vx.x * vx.x + vx.y * vx.y + vx.z * vx.z + vx.w * vx.w;
#pragma unroll
    for (int m = 1; m < 64; m <<= 1) ss += __shfl_xor(ss, m);
    __shared__ float wsum[4];
    if ((tid & 63) == 0) wsum[tid >> 6] = ss;
    __syncthreads();
    float tot = wsum[0] + wsum[1] + wsum[2] + wsum[3];
    float rs = rsqrtf(tot * (1.0f / 1024.0f) + 1e-6f);
    const float4* sr = (const float4*)scale;
    float4 sv = sr[tid];
    ushort4 r;
    r.x = f2b(vx.x * sv.x * rs);
    r.y = f2b(vx.y * sv.y * rs);
    r.z = f2b(vx.z * sv.z * rs);
    r.w = f2b(vx.w * sv.w * rs);
    *(ushort4*)(xn + (size_t)row * 1024 + tid * 4) = r;
}

// ---------------- f32 -> bf16 convert ----------------
__global__ void f2b_kernel(const float* __restrict__ in, unsigned short* __restrict__ outp, int n4) {
    int i = blockIdx.x * 256 + threadIdx.x;
    if (i < n4) {
        float4 vv = ((const float4*)in)[i];
        ushort4 r;
        r.x = f2b(vv.x);
        r.y = f2b(vv.y);
        r.z = f2b(vv.z);
        r.w = f2b(vv.w);
        ((ushort4*)outp)[i] = r;
    }
}

// ---------------- GEMM C = A * B^T (A: MxK bf16 row-major, B: NxK bf16 row-major) ----
// EPI 0: scatter qkv; RoPE fused for q,k (q scaled by QSC); v TRANSPOSED (B,H,D,S)
// EPI 1: out[m][n] = acc + skip[m][n]  (fp32)
constexpr int BM = 128, BN = 128, BK = 64, KDIM = 1024, NT = KDIM / BK;

template <int EPI>
__launch_bounds__(256, 2) __global__
    void gemm_bt(const unsigned short* __restrict__ A, const unsigned short* __restrict__ Bw,
                 unsigned short* __restrict__ qo, unsigned short* __restrict__ ko,
                 unsigned short* __restrict__ vo, const float* __restrict__ skip,
                 float* __restrict__ out, const float* __restrict__ theta) {
    __shared__ unsigned short As[2][BM * BK];
    __shared__ unsigned short Bs[2][BN * BK];
    const int tid = threadIdx.x;
    const int lane = tid & 63, w = tid >> 6;
    const int wr = w >> 1, wc = w & 1;
    const int lr = lane & 15, lg = lane >> 4;
    // XCD-aware bijective swizzle: each XCD gets 8 consecutive by-rows.
    constexpr int NBX = (EPI == 0) ? 24 : 8;
    const int f = blockIdx.x;
    const int xcd = f & 7, wloc = f >> 3;
    const int g = xcd * (NBX * 8) + wloc;
    const int bx = g % NBX, by = g / NBX;
    const int m0 = by * BM;
    const int n0 = bx * BN;
    const int NCOL = (EPI == 0) ? 3072 : 1024;

    f32x4 acc[4][4] = {};

    auto stage = [&](int buf, int kt) {
        const int k0 = kt * BK;
#pragma unroll
        for (int i = 0; i < 4; ++i) {
            int seg = i * 256 + tid;
            int row = seg >> 3, c8 = seg & 7;
            gl_lds16(A + (size_t)(m0 + row) * KDIM + k0 + c8 * 8,
                     &As[buf][(i * 256 + w * 64) * 8]);
            gl_lds16(Bw + (size_t)(n0 + row) * KDIM + k0 + c8 * 8,
                     &Bs[buf][(i * 256 + w * 64) * 8]);
        }
    };

    stage(0, 0);
    __syncthreads();
    int cur = 0;
    for (int kt = 0; kt < NT; ++kt) {
        if (kt + 1 < NT) stage(cur ^ 1, kt + 1);
#pragma unroll
        for (int kkc = 0; kkc < 2; ++kkc) {
            short8 a[4], b[4];
#pragma unroll
            for (int m = 0; m < 4; ++m)
                a[m] = *(const short8*)&As[cur][(wr * 64 + m * 16 + lr) * BK + kkc * 32 + lg * 8];
#pragma unroll
            for (int n = 0; n < 4; ++n)
                b[n] = *(const short8*)&Bs[cur][(wc * 64 + n * 16 + lr) * BK + kkc * 32 + lg * 8];
#pragma unroll
            for (int m = 0; m < 4; ++m)
#pragma unroll
                for (int n = 0; n < 4; ++n) acc[m][n] = MFMA16(a[m], b[n], acc[m][n]);
        }
        __syncthreads();
        cur ^= 1;
    }

    if (EPI == 0) {
        // whole (block, wc) group is one output tensor c and one head h
        const int colb = n0 + wc * 64;
        const int c = colb >> 10, h = (colb >> 6) & 15;
#pragma unroll
        for (int m = 0; m < 4; ++m) {
            int grow0 = m0 + wr * 64 + m * 16 + lg * 4;
            int b = grow0 >> 10, s0 = grow0 & 1023;
            if (c == 2) {
#pragma unroll
                for (int n = 0; n < 4; ++n) {
                    int d = n * 16 + lr;
                    ushort4 r;
                    r.x = f2b(acc[m][n][0]);
                    r.y = f2b(acc[m][n][1]);
                    r.z = f2b(acc[m][n][2]);
                    r.w = f2b(acc[m][n][3]);
                    *(ushort4*)&vo[(((size_t)(b * 16 + h)) * 64 + d) * 1024 + s0] = r;
                }
            } else {
                unsigned short* dst = (c == 0) ? qo : ko;
                float sc = (c == 0) ? QSC : 1.0f;
#pragma unroll
                for (int j = 0; j < 4; ++j) {
                    int s = s0 + j;
                    float th = theta[((s * 16 + h) << 4) + lr];
                    float sn, cs;
                    __sincosf(th, &sn, &cs);
                    float x1 = acc[m][0][j], x2 = acc[m][1][j];
                    size_t rowb = (((size_t)(b * 16 + h)) * 1024 + s) * 64;
                    dst[rowb + lr]      = f2b((x1 * cs - x2 * sn) * sc);
                    dst[rowb + 16 + lr] = f2b((x2 * cs + x1 * sn) * sc);
                    dst[rowb + 32 + lr] = f2b(acc[m][2][j] * sc);
                    dst[rowb + 48 + lr] = f2b(acc[m][3][j] * sc);
                }
            }
        }
    } else {
#pragma unroll
        for (int m = 0; m < 4; ++m)
#pragma unroll
            for (int n = 0; n < 4; ++n) {
                int gcol = n0 + wc * 64 + n * 16 + lr;
#pragma unroll
                for (int j = 0; j < 4; ++j) {
                    int grow = m0 + wr * 64 + m * 16 + lg * 4 + j;
                    size_t idx = (size_t)grow * NCOL + gcol;
                    out[idx] = acc[m][n][j] + skip[idx];
                }
            }
    }
}

// ---------------- Flash attention (causal), QBLK=128, swapped-operand ----------------
// q,k: (B,H,S,D) bf16 (q pre-scaled by QSC, rope applied).  vT: (B,H,D,S) bf16.
// o: (B,S,H*D) bf16. Swapped QK^T -> lane holds S^T[t][q=lr]; softmax in-register
// (2 shfls); P -> bf16 B-frag via shfl_xor lane<->reg-bit transpose (no LDS);
// PV computes O^T = mfma(V^T-frag, P-frag). 32 KB LDS -> 4 blocks/CU.
__launch_bounds__(256, 4) __global__
    void attn_kernel(const unsigned short* __restrict__ q, const unsigned short* __restrict__ k,
                     const unsigned short* __restrict__ vt, unsigned short* __restrict__ o) {
    constexpr int S = 1024, D = 64;
    __shared__ unsigned short Ks[2][64 * 64];  // [t][d], chunk-swizzled
    __shared__ unsigned short Vs[2][64 * 64];  // [d][t], chunk-swizzled
    const int tid = threadIdx.x, lane = tid & 63, w = tid >> 6;
    const int lr = lane & 15, lg = lane >> 4;
    const bool hi4 = (lane & 16) != 0;
    const bool hi5 = (lane & 32) != 0;
    // bijective: all 8 qb-tiles of a bh on one XCD; qmap balances 4-block groups to
    // exactly 36 kt-iters (16+2+14+4 / 12+6+10+8)
    const int f = blockIdx.x;  // 0..1023
    const int xcd = f & 7, slot = f >> 3;
    const int bh = xcd * 16 + (slot >> 3);
    const int qmap[8] = {7, 0, 6, 1, 5, 2, 4, 3};
    const int qb = qmap[slot & 7];
    const int qs = qb * 128;
    const size_t base = (size_t)bh * (S * D);
    const int wrow0 = qs + w * 32;

    short8 qf[2][2];
#pragma unroll
    for (int m = 0; m < 2; ++m) {
        const unsigned short* qp = q + base + (size_t)(wrow0 + m * 16 + lr) * D;
        qf[m][0] = *(const short8*)(qp + lg * 8);
        qf[m][1] = *(const short8*)(qp + 32 + lg * 8);
    }

    f32x4 of[2][4] = {};  // O^T[d = 16*n2 + lg*4 + j][q = wrow0 + m*16 + lr]
    float mrun[2] = {-1e30f, -1e30f};
    float lrun[2] = {0.f, 0.f};  // per-lane partial (own t-subset); reduced at end

    const int nkt = 2 * qb + 2;

    auto stageK = [&](int buf, int kt) {
#pragma unroll
        for (int i = 0; i < 2; ++i) {
            int seg = i * 256 + tid;
            int row = seg >> 3, c8 = (seg & 7) ^ (row & 7);
            gl_lds16(k + base + (size_t)(kt * 64 + row) * D + c8 * 8,
                     &Ks[buf][(i * 256 + w * 64) * 8]);
        }
    };
    auto stageV = [&](int buf, int kt) {
#pragma unroll
        for (int i = 0; i < 2; ++i) {
            int seg = i * 256 + tid;
            int row = seg >> 3, c8 = (seg & 7) ^ (row & 7);
            gl_lds16(vt + base + (size_t)row * S + kt * 64 + c8 * 8,
                     &Vs[buf][(i * 256 + w * 64) * 8]);
        }
    };

    stageK(0, 0);
    stageV(0, 0);
    __syncthreads();

    for (int kt = 0; kt < nkt; ++kt) {
        const int b = kt & 1;
        if (kt + 1 < nkt) {
            stageK(b ^ 1, kt + 1);
            stageV(b ^ 1, kt + 1);
        }

        if (kt * 64 <= wrow0 + 31) {  // wave-uniform: this wave has unmasked rows
            // Swapped QK^T: sf[m][n][j] = S^T[t = kt*64+16n+lg*4+j][q = wrow0+m*16+lr]
            f32x4 sf[2][4] = {};
#pragma unroll
            for (int n = 0; n < 4; ++n) {
                const int r = n * 16 + lr;
#pragma unroll
                for (int kkc = 0; kkc < 2; ++kkc) {
                    short8 kf = *(const short8*)&Ks[b][r * 64 + (((kkc * 4 + lg) ^ (lr & 7)) * 8)];
#pragma unroll
                    for (int m = 0; m < 2; ++m) sf[m][n] = MFMA16(kf, qf[m][kkc], sf[m][n]);
                }
            }

            if (kt * 64 + 63 > wrow0) {  // tile overlaps diagonal for this wave
#pragma unroll
                for (int m = 0; m < 2; ++m)
#pragma unroll
                    for (int n = 0; n < 4; ++n)
#pragma unroll
                        for (int j = 0; j < 4; ++j) {
                            int t = kt * 64 + 16 * n + lg * 4 + j;
                            int qr = wrow0 + m * 16 + lr;
                            if (t > qr) sf[m][n][j] = -1e30f;
                        }
            }

#pragma unroll
            for (int m = 0; m < 2; ++m) {
                // in-lane max over 16 t-values, then 2 shfls across the 4 lanes sharing q
                float mx = -1e30f;
#pragma unroll
                for (int n = 0; n < 4; ++n)
                    mx = fmaxf(mx, fmaxf(fmaxf(sf[m][n][0], sf[m][n][1]),
                                         fmaxf(sf[m][n][2], sf[m][n][3])));
                mx = fmaxf(mx, __shfl_xor(mx, 16));
                mx = fmaxf(mx, __shfl_xor(mx, 32));

                if (__any(mx > mrun[m] + 8.0f)) {
                    float newm = fmaxf(mrun[m], mx);
                    float sc = __builtin_amdgcn_exp2f(mrun[m] - newm);
                    mrun[m] = newm;
                    float psum = 0.f;
#pragma unroll
                    for (int n = 0; n < 4; ++n)
#pragma unroll
                        for (int j = 0; j < 4; ++j) {
                            float p = __builtin_amdgcn_exp2f(sf[m][n][j] - newm);
                            sf[m][n][j] = p;
                            psum += p;
                        }
                    lrun[m] = lrun[m] * sc + psum;
#pragma unroll
                    for (int n2 = 0; n2 < 4; ++n2) of[m][n2] *= sc;
                } else {
                    float mo = mrun[m];
                    float psum = 0.f;
#pragma unroll
                    for (int n = 0; n < 4; ++n)
#pragma unroll
                        for (int j = 0; j < 4; ++j) {
                            float p = __builtin_amdgcn_exp2f(sf[m][n][j] - mo);
                            sf[m][n][j] = p;
                            psum += p;
                        }
                    lrun[m] += psum;
                }
            }

            // P^T (regs) -> P B-frags via shfl_xor lane<->reg-bit transpose, no LDS.
            // Source dword Dk[n][w2] holds t-pair tp = 8n + 2lg + w2 (lo = even t), q = lr.
            // tp bits: [0]=w2 [1]=lane-b4 [2]=lane-b5 [3]=n0 [4]=n1.
            // Target: lane-b4=tp2, lane-b5=tp3, dword dd=(tp1,tp0), kkc=tp4.
            // xch32 (b5<->n0) then xch16 (b4<->pair-idx).
            short8 pfrag[2][2];  // [m][kkc]
#pragma unroll
            for (int m = 0; m < 2; ++m) {
                unsigned Dk[4][2];
#pragma unroll
                for (int n = 0; n < 4; ++n)
#pragma unroll
                    for (int w2 = 0; w2 < 2; ++w2)
                        Dk[n][w2] = (unsigned)f2b(sf[m][n][2 * w2]) |
                                    ((unsigned)f2b(sf[m][n][2 * w2 + 1]) << 16);
#pragma unroll
                for (int n1 = 0; n1 < 2; ++n1) {
                    unsigned fr[4];
#pragma unroll
                    for (int w2 = 0; w2 < 2; ++w2) {
                        unsigned A0 = Dk[2 * n1][w2];      // r=0 (n0=0)
                        unsigned A1 = Dk[2 * n1 + 1][w2];  // r=1 (n0=1)
                        // xch32: new(r',b5') = old(b5',r')
                        unsigned s0 = (unsigned)__shfl_xor((int)A0, 32);
                        unsigned s1 = (unsigned)__shfl_xor((int)A1, 32);
                        unsigned B0 = hi5 ? s1 : A0;
                        unsigned B1 = hi5 ? A1 : s0;
                        // xch16: new(r'',b4') = old(b4',r'')
                        s0 = (unsigned)__shfl_xor((int)B0, 16);
                        s1 = (unsigned)__shfl_xor((int)B1, 16);
                        unsigned C0 = hi4 ? s1 : B0;
                        unsigned C1 = hi4 ? B1 : s0;
                        fr[w2] = C0;      // dd = w2
                        fr[2 + w2] = C1;  // dd = 2 + w2
                    }
                    uint4v t4 = {fr[0], fr[1], fr[2], fr[3]};
                    pfrag[m][n1] = __builtin_bit_cast(short8, t4);
                }
            }

            // PV: O^T[d][q] += V^T[d][t] * P[q][t]
#pragma unroll
            for (int kkc = 0; kkc < 2; ++kkc) {
#pragma unroll
                for (int n2 = 0; n2 < 4; ++n2) {
                    const int r = n2 * 16 + lr;
                    short8 av = *(const short8*)&Vs[b][r * 64 + (((kkc * 4 + lg) ^ (lr & 7)) * 8)];
#pragma unroll
                    for (int m = 0; m < 2; ++m) of[m][n2] = MFMA16(av, pfrag[m][kkc], of[m][n2]);
                }
            }
        }

        __syncthreads();
    }

    const int bb = bh >> 4, h = bh & 15;
#pragma unroll
    for (int m = 0; m < 2; ++m) {
        float l = lrun[m];
        l += __shfl_xor(l, 16);
        l += __shfl_xor(l, 32);
        float inv = 1.f / l;
        int srow = wrow0 + m * 16 + lr;
        size_t ob = ((size_t)(bb * 1024 + srow)) * 1024 + h * 64;
#pragma unroll
        for (int n2 = 0; n2 < 4; ++n2) {
            ushort4 r;
            r.x = f2b(of[m][n2][0] * inv);
            r.y = f2b(of[m][n2][1] * inv);
            r.z = f2b(of[m][n2][2] * inv);
            r.w = f2b(of[m][n2][3] * inv);
            *(ushort4*)&o[ob + n2 * 16 + lg * 4] = r;
        }
    }
}

extern "C" void kernel_launch(void* const* d_in, const int* in_sizes, int n_in, void* d_out,
                              int out_size, void* d_ws, size_t ws_size, hipStream_t stream) {
    const float* x = (const float*)d_in[0];
    const float* scale = (const float*)d_in[1];
    const float* w_qkv = (const float*)d_in[2];
    const float* w_out = (const float*)d_in[3];
    const float* theta = (const float*)d_in[4];
    float* out = (float*)d_out;

    char* p = (char*)d_ws;
    unsigned short* xn = (unsigned short*)p;      p += (size_t)8192 * 1024 * 2;
    unsigned short* wqb = (unsigned short*)p;     p += (size_t)3072 * 1024 * 2;
    unsigned short* wob = (unsigned short*)p;     p += (size_t)1024 * 1024 * 2;
    unsigned short* qb_ = (unsigned short*)p;     p += (size_t)128 * 1024 * 64 * 2;
    unsigned short* kb_ = (unsigned short*)p;     p += (size_t)128 * 1024 * 64 * 2;
    unsigned short* vb_ = (unsigned short*)p;     p += (size_t)128 * 1024 * 64 * 2;  // V^T (B,H,D,S)
    unsigned short* ob_ = (unsigned short*)p;     p += (size_t)8192 * 1024 * 2;

    rmsnorm_kernel<<<8192, 256, 0, stream>>>(x, scale, xn);
    f2b_kernel<<<3072, 256, 0, stream>>>(w_qkv, wqb, 786432);
    f2b_kernel<<<1024, 256, 0, stream>>>(w_out, wob, 262144);
    gemm_bt<0><<<1536, 256, 0, stream>>>(xn, wqb, qb_, kb_, vb_, nullptr, nullptr, theta);
    attn_kernel<<<1024, 256, 0, stream>>>(qb_, kb_, vb_, ob_);
    gemm_bt<1><<<512, 256, 0, stream>>>(ob_, wob, nullptr, nullptr, nullptr, x, out, nullptr);
}

// Round 7
// 176.015 us; speedup vs baseline: 1.5312x; 1.2877x over previous
//
#include <hip/hip_runtime.h>
#include <hip/hip_bf16.h>
#include <cstdint>

typedef short short8 __attribute__((ext_vector_type(8)));
typedef float f32x4 __attribute__((ext_vector_type(4)));
typedef unsigned uint4v __attribute__((ext_vector_type(4)));

#define MFMA16(a, b, c) __builtin_amdgcn_mfma_f32_16x16x32_bf16((a), (b), (c), 0, 0, 0)

__device__ __forceinline__ unsigned short f2b(float f) {
    __hip_bfloat16 h = __float2bfloat16(f);
    return __builtin_bit_cast(unsigned short, h);
}

__device__ __forceinline__ void gl_lds16(const void* g, void* l) {
    __builtin_amdgcn_global_load_lds((const __attribute__((address_space(1))) void*)g,
                                     (__attribute__((address_space(3))) void*)l, 16, 0, 0);
}

// (1/8) * log2(e): QK^T scores land in log2 domain -> bare v_exp_f32 softmax
#define QSC 0.18033688011112042f

// ---------------- RMSNorm: fp32 x -> bf16 xn ----------------
__global__ void rmsnorm_kernel(const float* __restrict__ x, const float* __restrict__ scale,
                               unsigned short* __restrict__ xn) {
    const int row = blockIdx.x;
    const int tid = threadIdx.x;
    const float4* xr = (const float4*)(x + (size_t)row * 1024);
    float4 vx = xr[tid];
    float ss = vx.x * vx.x + vx.y * vx.y + vx.z * vx.z + vx.w * vx.w;
#pragma unroll
    for (int m = 1; m < 64; m <<= 1) ss += __shfl_xor(ss, m);
    __shared__ float wsum[4];
    if ((tid & 63) == 0) wsum[tid >> 6] = ss;
    __syncthreads();
    float tot = wsum[0] + wsum[1] + wsum[2] + wsum[3];
    float rs = rsqrtf(tot * (1.0f / 1024.0f) + 1e-6f);
    const float4* sr = (const float4*)scale;
    float4 sv = sr[tid];
    ushort4 r;
    r.x = f2b(vx.x * sv.x * rs);
    r.y = f2b(vx.y * sv.y * rs);
    r.z = f2b(vx.z * sv.z * rs);
    r.w = f2b(vx.w * sv.w * rs);
    *(ushort4*)(xn + (size_t)row * 1024 + tid * 4) = r;
}

// ---------------- f32 -> bf16 convert ----------------
__global__ void f2b_kernel(const float* __restrict__ in, unsigned short* __restrict__ outp, int n4) {
    int i = blockIdx.x * 256 + threadIdx.x;
    if (i < n4) {
        float4 vv = ((const float4*)in)[i];
        ushort4 r;
        r.x = f2b(vv.x);
        r.y = f2b(vv.y);
        r.z = f2b(vv.z);
        r.w = f2b(vv.w);
        ((ushort4*)outp)[i] = r;
    }
}

// ---------------- GEMM C = A * B^T (A: MxK bf16 row-major, B: NxK bf16 row-major) ----
// m97 structure: single-buffered 32 KB LDS, XOR chunk-swizzle (conflict-free ds_read_b128),
// global_load_lds width-16 staging, 2 barriers per K-step, high occupancy.
// EPI 0: scatter qkv; RoPE fused for q,k (q scaled by QSC); v TRANSPOSED (B,H,D,S)
// EPI 1: out[m][n] = acc + skip[m][n]  (fp32)
constexpr int BM = 128, BN = 128, BK = 64, KDIM = 1024, NT = KDIM / BK;

template <int EPI>
__launch_bounds__(256, 4) __global__
    void gemm_bt(const unsigned short* __restrict__ A, const unsigned short* __restrict__ Bw,
                 unsigned short* __restrict__ qo, unsigned short* __restrict__ ko,
                 unsigned short* __restrict__ vo, const float* __restrict__ skip,
                 float* __restrict__ out, const float* __restrict__ theta) {
    __shared__ unsigned short As[BM * BK];
    __shared__ unsigned short Bs[BN * BK];
    const int tid = threadIdx.x;
    const int lane = tid & 63, w = tid >> 6;
    const int wr = w >> 1, wc = w & 1;
    const int lr = lane & 15, lg = lane >> 4;
    // XCD-aware bijective swizzle: each XCD gets 8 consecutive by-rows.
    constexpr int NBX = (EPI == 0) ? 24 : 8;
    const int f = blockIdx.x;
    const int xcd = f & 7, wloc = f >> 3;
    const int g = xcd * (NBX * 8) + wloc;
    const int bx = g % NBX, by = g / NBX;
    const int m0 = by * BM;
    const int n0 = bx * BN;
    const int NCOL = (EPI == 0) ? 3072 : 1024;

    f32x4 acc[4][4] = {};

    // LDS[row][slot] = global[row][chunk slot ^ (row&7)]  (16B chunks, 8 per row)
    auto stage = [&](int kt) {
        const int k0 = kt * BK;
#pragma unroll
        for (int i = 0; i < 4; ++i) {
            int seg = i * 256 + tid;
            int row = seg >> 3, c8 = (seg & 7) ^ (row & 7);
            gl_lds16(A + (size_t)(m0 + row) * KDIM + k0 + c8 * 8, &As[(i * 256 + w * 64) * 8]);
            gl_lds16(Bw + (size_t)(n0 + row) * KDIM + k0 + c8 * 8, &Bs[(i * 256 + w * 64) * 8]);
        }
    };

    for (int kt = 0; kt < NT; ++kt) {
        stage(kt);
        __syncthreads();
#pragma unroll
        for (int kkc = 0; kkc < 2; ++kkc) {
            short8 a[4], b[4];
            const int slot = ((kkc * 4 + lg) ^ (lr & 7)) * 8;
#pragma unroll
            for (int m = 0; m < 4; ++m)
                a[m] = *(const short8*)&As[(wr * 64 + m * 16 + lr) * BK + slot];
#pragma unroll
            for (int n = 0; n < 4; ++n)
                b[n] = *(const short8*)&Bs[(wc * 64 + n * 16 + lr) * BK + slot];
#pragma unroll
            for (int m = 0; m < 4; ++m)
#pragma unroll
                for (int n = 0; n < 4; ++n) acc[m][n] = MFMA16(a[m], b[n], acc[m][n]);
        }
        __syncthreads();
    }

    if (EPI == 0) {
        // whole (block, wc) group is one output tensor c and one head h
        const int colb = n0 + wc * 64;
        const int c = colb >> 10, h = (colb >> 6) & 15;
#pragma unroll
        for (int m = 0; m < 4; ++m) {
            int grow0 = m0 + wr * 64 + m * 16 + lg * 4;
            int b = grow0 >> 10, s0 = grow0 & 1023;
            if (c == 2) {
#pragma unroll
                for (int n = 0; n < 4; ++n) {
                    int d = n * 16 + lr;
                    ushort4 r;
                    r.x = f2b(acc[m][n][0]);
                    r.y = f2b(acc[m][n][1]);
                    r.z = f2b(acc[m][n][2]);
                    r.w = f2b(acc[m][n][3]);
                    *(ushort4*)&vo[(((size_t)(b * 16 + h)) * 64 + d) * 1024 + s0] = r;
                }
            } else {
                unsigned short* dst = (c == 0) ? qo : ko;
                float sc = (c == 0) ? QSC : 1.0f;
#pragma unroll
                for (int j = 0; j < 4; ++j) {
                    int s = s0 + j;
                    float th = theta[((s * 16 + h) << 4) + lr];
                    float sn, cs;
                    __sincosf(th, &sn, &cs);
                    float x1 = acc[m][0][j], x2 = acc[m][1][j];
                    size_t rowb = (((size_t)(b * 16 + h)) * 1024 + s) * 64;
                    dst[rowb + lr]      = f2b((x1 * cs - x2 * sn) * sc);
                    dst[rowb + 16 + lr] = f2b((x2 * cs + x1 * sn) * sc);
                    dst[rowb + 32 + lr] = f2b(acc[m][2][j] * sc);
                    dst[rowb + 48 + lr] = f2b(acc[m][3][j] * sc);
                }
            }
        }
    } else {
#pragma unroll
        for (int m = 0; m < 4; ++m)
#pragma unroll
            for (int n = 0; n < 4; ++n) {
                int gcol = n0 + wc * 64 + n * 16 + lr;
#pragma unroll
                for (int j = 0; j < 4; ++j) {
                    int grow = m0 + wr * 64 + m * 16 + lg * 4 + j;
                    size_t idx = (size_t)grow * NCOL + gcol;
                    out[idx] = acc[m][n][j] + skip[idx];
                }
            }
    }
}

// ---------------- Flash attention (causal), QBLK=128, swapped-operand ----------------
// q,k: (B,H,S,D) bf16 (q pre-scaled by QSC, rope applied).  vT: (B,H,D,S) bf16.
// o: (B,S,H*D) bf16. Swapped QK^T -> lane holds S^T[t][q=lr]; softmax in-register
// (2 shfls); P -> bf16 B-frag via shfl_xor lane<->reg-bit transpose (no LDS);
// PV computes O^T = mfma(V^T-frag, P-frag). 32 KB LDS -> 4 blocks/CU.
__launch_bounds__(256, 4) __global__
    void attn_kernel(const unsigned short* __restrict__ q, const unsigned short* __restrict__ k,
                     const unsigned short* __restrict__ vt, unsigned short* __restrict__ o) {
    constexpr int S = 1024, D = 64;
    __shared__ unsigned short Ks[2][64 * 64];  // [t][d], chunk-swizzled
    __shared__ unsigned short Vs[2][64 * 64];  // [d][t], chunk-swizzled
    const int tid = threadIdx.x, lane = tid & 63, w = tid >> 6;
    const int lr = lane & 15, lg = lane >> 4;
    const bool hi4 = (lane & 16) != 0;
    const bool hi5 = (lane & 32) != 0;
    // bijective: all 8 qb-tiles of a bh on one XCD; qmap balances 4-block groups to
    // exactly 36 kt-iters (16+2+14+4 / 12+6+10+8)
    const int f = blockIdx.x;  // 0..1023
    const int xcd = f & 7, slot = f >> 3;
    const int bh = xcd * 16 + (slot >> 3);
    const int qmap[8] = {7, 0, 6, 1, 5, 2, 4, 3};
    const int qb = qmap[slot & 7];
    const int qs = qb * 128;
    const size_t base = (size_t)bh * (S * D);
    const int wrow0 = qs + w * 32;

    short8 qf[2][2];
#pragma unroll
    for (int m = 0; m < 2; ++m) {
        const unsigned short* qp = q + base + (size_t)(wrow0 + m * 16 + lr) * D;
        qf[m][0] = *(const short8*)(qp + lg * 8);
        qf[m][1] = *(const short8*)(qp + 32 + lg * 8);
    }

    f32x4 of[2][4] = {};  // O^T[d = 16*n2 + lg*4 + j][q = wrow0 + m*16 + lr]
    float mrun[2] = {-1e30f, -1e30f};
    float lrun[2] = {0.f, 0.f};  // per-lane partial (own t-subset); reduced at end

    const int nkt = 2 * qb + 2;

    auto stageK = [&](int buf, int kt) {
#pragma unroll
        for (int i = 0; i < 2; ++i) {
            int seg = i * 256 + tid;
            int row = seg >> 3, c8 = (seg & 7) ^ (row & 7);
            gl_lds16(k + base + (size_t)(kt * 64 + row) * D + c8 * 8,
                     &Ks[buf][(i * 256 + w * 64) * 8]);
        }
    };
    auto stageV = [&](int buf, int kt) {
#pragma unroll
        for (int i = 0; i < 2; ++i) {
            int seg = i * 256 + tid;
            int row = seg >> 3, c8 = (seg & 7) ^ (row & 7);
            gl_lds16(vt + base + (size_t)row * S + kt * 64 + c8 * 8,
                     &Vs[buf][(i * 256 + w * 64) * 8]);
        }
    };

    stageK(0, 0);
    stageV(0, 0);
    __syncthreads();

    for (int kt = 0; kt < nkt; ++kt) {
        const int b = kt & 1;
        if (kt + 1 < nkt) {
            stageK(b ^ 1, kt + 1);
            stageV(b ^ 1, kt + 1);
        }

        if (kt * 64 <= wrow0 + 31) {  // wave-uniform: this wave has unmasked rows
            // Swapped QK^T: sf[m][n][j] = S^T[t = kt*64+16n+lg*4+j][q = wrow0+m*16+lr]
            f32x4 sf[2][4] = {};
#pragma unroll
            for (int n = 0; n < 4; ++n) {
                const int r = n * 16 + lr;
#pragma unroll
                for (int kkc = 0; kkc < 2; ++kkc) {
                    short8 kf = *(const short8*)&Ks[b][r * 64 + (((kkc * 4 + lg) ^ (lr & 7)) * 8)];
#pragma unroll
                    for (int m = 0; m < 2; ++m) sf[m][n] = MFMA16(kf, qf[m][kkc], sf[m][n]);
                }
            }

            if (kt * 64 + 63 > wrow0) {  // tile overlaps diagonal for this wave
#pragma unroll
                for (int m = 0; m < 2; ++m)
#pragma unroll
                    for (int n = 0; n < 4; ++n)
#pragma unroll
                        for (int j = 0; j < 4; ++j) {
                            int t = kt * 64 + 16 * n + lg * 4 + j;
                            int qr = wrow0 + m * 16 + lr;
                            if (t > qr) sf[m][n][j] = -1e30f;
                        }
            }

#pragma unroll
            for (int m = 0; m < 2; ++m) {
                // in-lane max over 16 t-values, then 2 shfls across the 4 lanes sharing q
                float mx = -1e30f;
#pragma unroll
                for (int n = 0; n < 4; ++n)
                    mx = fmaxf(mx, fmaxf(fmaxf(sf[m][n][0], sf[m][n][1]),
                                         fmaxf(sf[m][n][2], sf[m][n][3])));
                mx = fmaxf(mx, __shfl_xor(mx, 16));
                mx = fmaxf(mx, __shfl_xor(mx, 32));

                if (__any(mx > mrun[m] + 8.0f)) {
                    float newm = fmaxf(mrun[m], mx);
                    float sc = __builtin_amdgcn_exp2f(mrun[m] - newm);
                    mrun[m] = newm;
                    float psum = 0.f;
#pragma unroll
                    for (int n = 0; n < 4; ++n)
#pragma unroll
                        for (int j = 0; j < 4; ++j) {
                            float p = __builtin_amdgcn_exp2f(sf[m][n][j] - newm);
                            sf[m][n][j] = p;
                            psum += p;
                        }
                    lrun[m] = lrun[m] * sc + psum;
#pragma unroll
                    for (int n2 = 0; n2 < 4; ++n2) of[m][n2] *= sc;
                } else {
                    float mo = mrun[m];
                    float psum = 0.f;
#pragma unroll
                    for (int n = 0; n < 4; ++n)
#pragma unroll
                        for (int j = 0; j < 4; ++j) {
                            float p = __builtin_amdgcn_exp2f(sf[m][n][j] - mo);
                            sf[m][n][j] = p;
                            psum += p;
                        }
                    lrun[m] += psum;
                }
            }

            // P^T (regs) -> P B-frags via shfl_xor lane<->reg-bit transpose, no LDS.
            // Source dword Dk[n][w2] holds t-pair tp = 8n + 2lg + w2 (lo = even t), q = lr.
            // tp bits: [0]=w2 [1]=lane-b4 [2]=lane-b5 [3]=n0 [4]=n1.
            // Target: lane-b4=tp2, lane-b5=tp3, dword dd=(tp1,tp0), kkc=tp4.
            // xch32 (b5<->n0) then xch16 (b4<->pair-idx).
            short8 pfrag[2][2];  // [m][kkc]
#pragma unroll
            for (int m = 0; m < 2; ++m) {
                unsigned Dk[4][2];
#pragma unroll
                for (int n = 0; n < 4; ++n)
#pragma unroll
                    for (int w2 = 0; w2 < 2; ++w2)
                        Dk[n][w2] = (unsigned)f2b(sf[m][n][2 * w2]) |
                                    ((unsigned)f2b(sf[m][n][2 * w2 + 1]) << 16);
#pragma unroll
                for (int n1 = 0; n1 < 2; ++n1) {
                    unsigned fr[4];
#pragma unroll
                    for (int w2 = 0; w2 < 2; ++w2) {
                        unsigned A0 = Dk[2 * n1][w2];      // r=0 (n0=0)
                        unsigned A1 = Dk[2 * n1 + 1][w2];  // r=1 (n0=1)
                        // xch32: new(r',b5') = old(b5',r')
                        unsigned s0 = (unsigned)__shfl_xor((int)A0, 32);
                        unsigned s1 = (unsigned)__shfl_xor((int)A1, 32);
                        unsigned B0 = hi5 ? s1 : A0;
                        unsigned B1 = hi5 ? A1 : s0;
                        // xch16: new(r'',b4') = old(b4',r'')
                        s0 = (unsigned)__shfl_xor((int)B0, 16);
                        s1 = (unsigned)__shfl_xor((int)B1, 16);
                        unsigned C0 = hi4 ? s1 : B0;
                        unsigned C1 = hi4 ? B1 : s0;
                        fr[w2] = C0;      // dd = w2
                        fr[2 + w2] = C1;  // dd = 2 + w2
                    }
                    uint4v t4 = {fr[0], fr[1], fr[2], fr[3]};
                    pfrag[m][n1] = __builtin_bit_cast(short8, t4);
                }
            }

            // PV: O^T[d][q] += V^T[d][t] * P[q][t]
#pragma unroll
            for (int kkc = 0; kkc < 2; ++kkc) {
#pragma unroll
                for (int n2 = 0; n2 < 4; ++n2) {
                    const int r = n2 * 16 + lr;
                    short8 av = *(const short8*)&Vs[b][r * 64 + (((kkc * 4 + lg) ^ (lr & 7)) * 8)];
#pragma unroll
                    for (int m = 0; m < 2; ++m) of[m][n2] = MFMA16(av, pfrag[m][kkc], of[m][n2]);
                }
            }
        }

        __syncthreads();
    }

    const int bb = bh >> 4, h = bh & 15;
#pragma unroll
    for (int m = 0; m < 2; ++m) {
        float l = lrun[m];
        l += __shfl_xor(l, 16);
        l += __shfl_xor(l, 32);
        float inv = 1.f / l;
        int srow = wrow0 + m * 16 + lr;
        size_t ob = ((size_t)(bb * 1024 + srow)) * 1024 + h * 64;
#pragma unroll
        for (int n2 = 0; n2 < 4; ++n2) {
            ushort4 r;
            r.x = f2b(of[m][n2][0] * inv);
            r.y = f2b(of[m][n2][1] * inv);
            r.z = f2b(of[m][n2][2] * inv);
            r.w = f2b(of[m][n2][3] * inv);
            *(ushort4*)&o[ob + n2 * 16 + lg * 4] = r;
        }
    }
}

extern "C" void kernel_launch(void* const* d_in, const int* in_sizes, int n_in, void* d_out,
                              int out_size, void* d_ws, size_t ws_size, hipStream_t stream) {
    const float* x = (const float*)d_in[0];
    const float* scale = (const float*)d_in[1];
    const float* w_qkv = (const float*)d_in[2];
    const float* w_out = (const float*)d_in[3];
    const float* theta = (const float*)d_in[4];
    float* out = (float*)d_out;

    char* p = (char*)d_ws;
    unsigned short* xn = (unsigned short*)p;      p += (size_t)8192 * 1024 * 2;
    unsigned short* wqb = (unsigned short*)p;     p += (size_t)3072 * 1024 * 2;
    unsigned short* wob = (unsigned short*)p;     p += (size_t)1024 * 1024 * 2;
    unsigned short* qb_ = (unsigned short*)p;     p += (size_t)128 * 1024 * 64 * 2;
    unsigned short* kb_ = (unsigned short*)p;     p += (size_t)128 * 1024 * 64 * 2;
    unsigned short* vb_ = (unsigned short*)p;     p += (size_t)128 * 1024 * 64 * 2;  // V^T (B,H,D,S)
    unsigned short* ob_ = (unsigned short*)p;     p += (size_t)8192 * 1024 * 2;

    rmsnorm_kernel<<<8192, 256, 0, stream>>>(x, scale, xn);
    f2b_kernel<<<3072, 256, 0, stream>>>(w_qkv, wqb, 786432);
    f2b_kernel<<<1024, 256, 0, stream>>>(w_out, wob, 262144);
    gemm_bt<0><<<1536, 256, 0, stream>>>(xn, wqb, qb_, kb_, vb_, nullptr, nullptr, theta);
    attn_kernel<<<1024, 256, 0, stream>>>(qb_, kb_, vb_, ob_);
    gemm_bt<1><<<512, 256, 0, stream>>>(ob_, wob, nullptr, nullptr, nullptr, x, out, nullptr);
}

// Round 8
// 161.380 us; speedup vs baseline: 1.6701x; 1.0907x over previous
//
#include <hip/hip_runtime.h>
#include <hip/hip_bf16.h>
#include <cstdint>

typedef short short8 __attribute__((ext_vector_type(8)));
typedef float f32x4 __attribute__((ext_vector_type(4)));

#define MFMA16(a, b, c) __builtin_amdgcn_mfma_f32_16x16x32_bf16((a), (b), (c), 0, 0, 0)

__device__ __forceinline__ unsigned short f2b(float f) {
    __hip_bfloat16 h = __float2bfloat16(f);
    return __builtin_bit_cast(unsigned short, h);
}

__device__ __forceinline__ void gl_lds16(const void* g, void* l) {
    __builtin_amdgcn_global_load_lds((const __attribute__((address_space(1))) void*)g,
                                     (__attribute__((address_space(3))) void*)l, 16, 0, 0);
}

// (1/8) * log2(e): QK^T scores land in log2 domain -> bare v_exp_f32 softmax
#define QSC 0.18033688011112042f

// ---------------- RMSNorm: fp32 x -> bf16 xn ----------------
__global__ void rmsnorm_kernel(const float* __restrict__ x, const float* __restrict__ scale,
                               unsigned short* __restrict__ xn) {
    const int row = blockIdx.x;
    const int tid = threadIdx.x;
    const float4* xr = (const float4*)(x + (size_t)row * 1024);
    float4 vx = xr[tid];
    float ss = vx.x * vx.x + vx.y * vx.y + vx.z * vx.z + vx.w * vx.w;
#pragma unroll
    for (int m = 1; m < 64; m <<= 1) ss += __shfl_xor(ss, m);
    __shared__ float wsum[4];
    if ((tid & 63) == 0) wsum[tid >> 6] = ss;
    __syncthreads();
    float tot = wsum[0] + wsum[1] + wsum[2] + wsum[3];
    float rs = rsqrtf(tot * (1.0f / 1024.0f) + 1e-6f);
    const float4* sr = (const float4*)scale;
    float4 sv = sr[tid];
    ushort4 r;
    r.x = f2b(vx.x * sv.x * rs);
    r.y = f2b(vx.y * sv.y * rs);
    r.z = f2b(vx.z * sv.z * rs);
    r.w = f2b(vx.w * sv.w * rs);
    *(ushort4*)(xn + (size_t)row * 1024 + tid * 4) = r;
}

// ---------------- f32 -> bf16 convert ----------------
__global__ void f2b_kernel(const float* __restrict__ in, unsigned short* __restrict__ outp, int n4) {
    int i = blockIdx.x * 256 + threadIdx.x;
    if (i < n4) {
        float4 vv = ((const float4*)in)[i];
        ushort4 r;
        r.x = f2b(vv.x);
        r.y = f2b(vv.y);
        r.z = f2b(vv.z);
        r.w = f2b(vv.w);
        ((ushort4*)outp)[i] = r;
    }
}

// ---------------- GEMM C = A * B^T (A: MxK bf16 row-major, B: NxK bf16 row-major) ----
// m97 structure: single-buffered 32 KB LDS, XOR chunk-swizzle (conflict-free ds_read_b128),
// global_load_lds width-16 staging, 2 barriers per K-step, high occupancy.
// EPI 0: scatter qkv; RoPE fused for q,k (q scaled by QSC); v TRANSPOSED (B,H,D,S)
// EPI 1: out[m][n] = acc + skip[m][n]  (fp32)
constexpr int BM = 128, BN = 128, BK = 64, KDIM = 1024, NT = KDIM / BK;

template <int EPI>
__launch_bounds__(256, 4) __global__
    void gemm_bt(const unsigned short* __restrict__ A, const unsigned short* __restrict__ Bw,
                 unsigned short* __restrict__ qo, unsigned short* __restrict__ ko,
                 unsigned short* __restrict__ vo, const float* __restrict__ skip,
                 float* __restrict__ out, const float* __restrict__ theta) {
    __shared__ unsigned short As[BM * BK];
    __shared__ unsigned short Bs[BN * BK];
    const int tid = threadIdx.x;
    const int lane = tid & 63, w = tid >> 6;
    const int wr = w >> 1, wc = w & 1;
    const int lr = lane & 15, lg = lane >> 4;
    // XCD-aware bijective swizzle: each XCD gets 8 consecutive by-rows.
    constexpr int NBX = (EPI == 0) ? 24 : 8;
    const int f = blockIdx.x;
    const int xcd = f & 7, wloc = f >> 3;
    const int g = xcd * (NBX * 8) + wloc;
    const int bx = g % NBX, by = g / NBX;
    const int m0 = by * BM;
    const int n0 = bx * BN;
    const int NCOL = (EPI == 0) ? 3072 : 1024;

    f32x4 acc[4][4] = {};

    // LDS[row][slot] = global[row][chunk slot ^ (row&7)]  (16B chunks, 8 per row)
    auto stage = [&](int kt) {
        const int k0 = kt * BK;
#pragma unroll
        for (int i = 0; i < 4; ++i) {
            int seg = i * 256 + tid;
            int row = seg >> 3, c8 = (seg & 7) ^ (row & 7);
            gl_lds16(A + (size_t)(m0 + row) * KDIM + k0 + c8 * 8, &As[(i * 256 + w * 64) * 8]);
            gl_lds16(Bw + (size_t)(n0 + row) * KDIM + k0 + c8 * 8, &Bs[(i * 256 + w * 64) * 8]);
        }
    };

    for (int kt = 0; kt < NT; ++kt) {
        stage(kt);
        __syncthreads();
#pragma unroll
        for (int kkc = 0; kkc < 2; ++kkc) {
            short8 a[4], b[4];
            const int slot = ((kkc * 4 + lg) ^ (lr & 7)) * 8;
#pragma unroll
            for (int m = 0; m < 4; ++m)
                a[m] = *(const short8*)&As[(wr * 64 + m * 16 + lr) * BK + slot];
#pragma unroll
            for (int n = 0; n < 4; ++n)
                b[n] = *(const short8*)&Bs[(wc * 64 + n * 16 + lr) * BK + slot];
#pragma unroll
            for (int m = 0; m < 4; ++m)
#pragma unroll
                for (int n = 0; n < 4; ++n) acc[m][n] = MFMA16(a[m], b[n], acc[m][n]);
        }
        __syncthreads();
    }

    if (EPI == 0) {
        // whole (block, wc) group is one output tensor c and one head h
        const int colb = n0 + wc * 64;
        const int c = colb >> 10, h = (colb >> 6) & 15;
#pragma unroll
        for (int m = 0; m < 4; ++m) {
            int grow0 = m0 + wr * 64 + m * 16 + lg * 4;
            int b = grow0 >> 10, s0 = grow0 & 1023;
            if (c == 2) {
#pragma unroll
                for (int n = 0; n < 4; ++n) {
                    int d = n * 16 + lr;
                    ushort4 r;
                    r.x = f2b(acc[m][n][0]);
                    r.y = f2b(acc[m][n][1]);
                    r.z = f2b(acc[m][n][2]);
                    r.w = f2b(acc[m][n][3]);
                    *(ushort4*)&vo[(((size_t)(b * 16 + h)) * 64 + d) * 1024 + s0] = r;
                }
            } else {
                unsigned short* dst = (c == 0) ? qo : ko;
                float sc = (c == 0) ? QSC : 1.0f;
#pragma unroll
                for (int j = 0; j < 4; ++j) {
                    int s = s0 + j;
                    float th = theta[((s * 16 + h) << 4) + lr];
                    float sn, cs;
                    __sincosf(th, &sn, &cs);
                    float x1 = acc[m][0][j], x2 = acc[m][1][j];
                    size_t rowb = (((size_t)(b * 16 + h)) * 1024 + s) * 64;
                    dst[rowb + lr]      = f2b((x1 * cs - x2 * sn) * sc);
                    dst[rowb + 16 + lr] = f2b((x2 * cs + x1 * sn) * sc);
                    dst[rowb + 32 + lr] = f2b(acc[m][2][j] * sc);
                    dst[rowb + 48 + lr] = f2b(acc[m][3][j] * sc);
                }
            }
        }
    } else {
#pragma unroll
        for (int m = 0; m < 4; ++m)
#pragma unroll
            for (int n = 0; n < 4; ++n) {
                int gcol = n0 + wc * 64 + n * 16 + lr;
#pragma unroll
                for (int j = 0; j < 4; ++j) {
                    int grow = m0 + wr * 64 + m * 16 + lg * 4 + j;
                    size_t idx = (size_t)grow * NCOL + gcol;
                    out[idx] = acc[m][n][j] + skip[idx];
                }
            }
    }
}

// ---------------- Flash attention (causal), QBLK=128, swapped-operand ----------------
// q,k: (B,H,S,D) bf16 (q pre-scaled by QSC, rope applied).  vT: (B,H,D,S) bf16.
// o: (B,S,H*D) bf16. Swapped QK^T -> lane holds S^T[t][q=lr]; softmax in-register
// (2 shfls). P routed to PV A-fragment via a wave-private XOR-swizzled LDS dword
// scratch (8 ds_write_b32 + 2 ds_read_b128 per m; no barriers, no bpermutes).
// PV computes O = mfma(P, V^T-frag). LPT block order (heavy qb first) with
// bh->XCD binding preserved. 40 KB LDS -> 4 blocks/CU.
__launch_bounds__(256, 4) __global__
    void attn_kernel(const unsigned short* __restrict__ q, const unsigned short* __restrict__ k,
                     const unsigned short* __restrict__ vt, unsigned short* __restrict__ o) {
    constexpr int S = 1024, D = 64;
    __shared__ unsigned short Ks[2][64 * 64];  // [t][d], chunk-swizzled
    __shared__ unsigned short Vs[2][64 * 64];  // [d][t], chunk-swizzled
    __shared__ unsigned Pls[4][16 * 32];       // per-wave P dwords, XOR-swizzled
    const int tid = threadIdx.x, lane = tid & 63, w = tid >> 6;
    const int lr = lane & 15, lg = lane >> 4;
    // LPT: stripes of 128 blocks, qb descending; bh->XCD binding invariant across
    // stripes (f&7 selects xcd for the same 16 bh every stripe).
    const int f = blockIdx.x;  // 0..1023
    const int r0 = f & 127;
    const int qb = 7 - (f >> 7);
    const int bh = (r0 & 7) * 16 + (r0 >> 3);
    const int qs = qb * 128;
    const size_t base = (size_t)bh * (S * D);
    const int wrow0 = qs + w * 32;

    short8 qf[2][2];
#pragma unroll
    for (int m = 0; m < 2; ++m) {
        const unsigned short* qp = q + base + (size_t)(wrow0 + m * 16 + lr) * D;
        qf[m][0] = *(const short8*)(qp + lg * 8);
        qf[m][1] = *(const short8*)(qp + 32 + lg * 8);
    }

    f32x4 of[2][4] = {};  // O[q = wrow0 + m*16 + lg*4 + j][d = 16*n2 + lr]
    float mrun[2] = {-1e30f, -1e30f};
    float lrun[2] = {0.f, 0.f};  // per-lane partial (own t-subset); reduced at end

    const int nkt = 2 * qb + 2;

    auto stageK = [&](int buf, int kt) {
#pragma unroll
        for (int i = 0; i < 2; ++i) {
            int seg = i * 256 + tid;
            int row = seg >> 3, c8 = (seg & 7) ^ (row & 7);
            gl_lds16(k + base + (size_t)(kt * 64 + row) * D + c8 * 8,
                     &Ks[buf][(i * 256 + w * 64) * 8]);
        }
    };
    auto stageV = [&](int buf, int kt) {
#pragma unroll
        for (int i = 0; i < 2; ++i) {
            int seg = i * 256 + tid;
            int row = seg >> 3, c8 = (seg & 7) ^ (row & 7);
            gl_lds16(vt + base + (size_t)row * S + kt * 64 + c8 * 8,
                     &Vs[buf][(i * 256 + w * 64) * 8]);
        }
    };

    unsigned* Pw = &Pls[w][0];
    const int swz = (lr & 3) << 3;

    stageK(0, 0);
    stageV(0, 0);
    __syncthreads();

    for (int kt = 0; kt < nkt; ++kt) {
        const int b = kt & 1;
        if (kt + 1 < nkt) {
            stageK(b ^ 1, kt + 1);
            stageV(b ^ 1, kt + 1);
        }

        if (kt * 64 <= wrow0 + 31) {  // wave-uniform: this wave has unmasked rows
            // Swapped QK^T: sf[m][n][j] = S^T[t = kt*64+16n+lg*4+j][q = wrow0+m*16+lr]
            f32x4 sf[2][4] = {};
            __builtin_amdgcn_s_setprio(1);
#pragma unroll
            for (int n = 0; n < 4; ++n) {
                const int r = n * 16 + lr;
#pragma unroll
                for (int kkc = 0; kkc < 2; ++kkc) {
                    short8 kf = *(const short8*)&Ks[b][r * 64 + (((kkc * 4 + lg) ^ (lr & 7)) * 8)];
#pragma unroll
                    for (int m = 0; m < 2; ++m) sf[m][n] = MFMA16(kf, qf[m][kkc], sf[m][n]);
                }
            }
            __builtin_amdgcn_s_setprio(0);

            if (kt * 64 + 63 > wrow0) {  // tile overlaps diagonal for this wave
#pragma unroll
                for (int m = 0; m < 2; ++m)
#pragma unroll
                    for (int n = 0; n < 4; ++n)
#pragma unroll
                        for (int j = 0; j < 4; ++j) {
                            int t = kt * 64 + 16 * n + lg * 4 + j;
                            int qr = wrow0 + m * 16 + lr;
                            if (t > qr) sf[m][n][j] = -1e30f;
                        }
            }

#pragma unroll
            for (int m = 0; m < 2; ++m) {
                // in-lane max over 16 t-values, then 2 shfls across the 4 lanes sharing q
                float mx = -1e30f;
#pragma unroll
                for (int n = 0; n < 4; ++n)
                    mx = fmaxf(mx, fmaxf(fmaxf(sf[m][n][0], sf[m][n][1]),
                                         fmaxf(sf[m][n][2], sf[m][n][3])));
                mx = fmaxf(mx, __shfl_xor(mx, 16));
                mx = fmaxf(mx, __shfl_xor(mx, 32));

                if (__any(mx > mrun[m] + 8.0f)) {
                    float newm = fmaxf(mrun[m], mx);
                    float sc = __builtin_amdgcn_exp2f(mrun[m] - newm);
                    mrun[m] = newm;
                    float psum = 0.f;
#pragma unroll
                    for (int n = 0; n < 4; ++n)
#pragma unroll
                        for (int j = 0; j < 4; ++j) {
                            float p = __builtin_amdgcn_exp2f(sf[m][n][j] - newm);
                            sf[m][n][j] = p;
                            psum += p;
                        }
                    lrun[m] = lrun[m] * sc + psum;
#pragma unroll
                    for (int n2 = 0; n2 < 4; ++n2) of[m][n2] *= sc;
                } else {
                    float mo = mrun[m];
                    float psum = 0.f;
#pragma unroll
                    for (int n = 0; n < 4; ++n)
#pragma unroll
                        for (int j = 0; j < 4; ++j) {
                            float p = __builtin_amdgcn_exp2f(sf[m][n][j] - mo);
                            sf[m][n][j] = p;
                            psum += p;
                        }
                    lrun[m] += psum;
                }
            }

            // P -> PV A-frags through wave-private LDS dwords.
            // Write: dword tp = 8n+2lg+w2 holds t = {2tp, 2tp+1} for q-row lr.
            // Read:  A-frag k-layout t = kkc*32 + 8lg + j  -> dwords tp = kkc*16+4lg+{0..3}.
            // XOR swz spreads banks; bijective per row.
            short8 pa[2][2];  // [m][kkc]
#pragma unroll
            for (int m = 0; m < 2; ++m) {
                unsigned Dk[4][2];
#pragma unroll
                for (int n = 0; n < 4; ++n)
#pragma unroll
                    for (int w2 = 0; w2 < 2; ++w2)
                        Dk[n][w2] = (unsigned)f2b(sf[m][n][2 * w2]) |
                                    ((unsigned)f2b(sf[m][n][2 * w2 + 1]) << 16);
#pragma unroll
                for (int n = 0; n < 4; ++n)
#pragma unroll
                    for (int w2 = 0; w2 < 2; ++w2)
                        Pw[lr * 32 + ((8 * n + 2 * lg + w2) ^ swz)] = Dk[n][w2];
#pragma unroll
                for (int kkc = 0; kkc < 2; ++kkc)
                    pa[m][kkc] = *(const short8*)&Pw[lr * 32 + ((kkc * 16 + 4 * lg) ^ swz)];
            }

            // PV: O[q][d] += P[q][t] * V[t][d]; V^T-frag read identical to K-frag
            __builtin_amdgcn_s_setprio(1);
#pragma unroll
            for (int kkc = 0; kkc < 2; ++kkc) {
#pragma unroll
                for (int n2 = 0; n2 < 4; ++n2) {
                    const int r = n2 * 16 + lr;
                    short8 bv = *(const short8*)&Vs[b][r * 64 + (((kkc * 4 + lg) ^ (lr & 7)) * 8)];
#pragma unroll
                    for (int m = 0; m < 2; ++m) of[m][n2] = MFMA16(pa[m][kkc], bv, of[m][n2]);
                }
            }
            __builtin_amdgcn_s_setprio(0);
        }

        __syncthreads();
    }

    // final l per q-row, redistributed through the wave-private scratch
    float* Lw = (float*)&Pls[w][0];
#pragma unroll
    for (int m = 0; m < 2; ++m) {
        float l = lrun[m];
        l += __shfl_xor(l, 16);
        l += __shfl_xor(l, 32);
        Lw[m * 16 + lr] = l;  // all lg write the same value
    }
    const int bb = bh >> 4, h = bh & 15;
#pragma unroll
    for (int m = 0; m < 2; ++m)
#pragma unroll
        for (int j = 0; j < 4; ++j) {
            float inv = 1.f / Lw[m * 16 + lg * 4 + j];
            int srow = wrow0 + m * 16 + lg * 4 + j;
            size_t ob = ((size_t)(bb * 1024 + srow)) * 1024 + h * 64;
#pragma unroll
            for (int n2 = 0; n2 < 4; ++n2)
                o[ob + n2 * 16 + lr] = f2b(of[m][n2][j] * inv);
        }
}

extern "C" void kernel_launch(void* const* d_in, const int* in_sizes, int n_in, void* d_out,
                              int out_size, void* d_ws, size_t ws_size, hipStream_t stream) {
    const float* x = (const float*)d_in[0];
    const float* scale = (const float*)d_in[1];
    const float* w_qkv = (const float*)d_in[2];
    const float* w_out = (const float*)d_in[3];
    const float* theta = (const float*)d_in[4];
    float* out = (float*)d_out;

    char* p = (char*)d_ws;
    unsigned short* xn = (unsigned short*)p;      p += (size_t)8192 * 1024 * 2;
    unsigned short* wqb = (unsigned short*)p;     p += (size_t)3072 * 1024 * 2;
    unsigned short* wob = (unsigned short*)p;     p += (size_t)1024 * 1024 * 2;
    unsigned short* qb_ = (unsigned short*)p;     p += (size_t)128 * 1024 * 64 * 2;
    unsigned short* kb_ = (unsigned short*)p;     p += (size_t)128 * 1024 * 64 * 2;
    unsigned short* vb_ = (unsigned short*)p;     p += (size_t)128 * 1024 * 64 * 2;  // V^T (B,H,D,S)
    unsigned short* ob_ = (unsigned short*)p;     p += (size_t)8192 * 1024 * 2;

    rmsnorm_kernel<<<8192, 256, 0, stream>>>(x, scale, xn);
    f2b_kernel<<<3072, 256, 0, stream>>>(w_qkv, wqb, 786432);
    f2b_kernel<<<1024, 256, 0, stream>>>(w_out, wob, 262144);
    gemm_bt<0><<<1536, 256, 0, stream>>>(xn, wqb, qb_, kb_, vb_, nullptr, nullptr, theta);
    attn_kernel<<<1024, 256, 0, stream>>>(qb_, kb_, vb_, ob_);
    gemm_bt<1><<<512, 256, 0, stream>>>(ob_, wob, nullptr, nullptr, nullptr, x, out, nullptr);
}